// Round 1
// baseline (77842.572 us; speedup 1.0000x reference)
//
#include <hip/hip_runtime.h>
#include <math.h>

// ESN reservoir: h_t = tanh(x_t Win^T + h_{t-1} W^T); out_t = h_t Wout^T + b
// Strategy (round 1, correctness-first):
//   - One kernel per timestep, 2048 stream-ordered launches (graph nodes).
//   - Grid 256 blocks x 256 threads. Block owns 8 rows of h; each wave owns 2.
//   - Lanes split K (2048) into float4 chunks: fully coalesced W reads
//     (64 lanes x 16B = 1KB/instr). h_prev (128KB) is L2-hot.
//   - Cross-lane reduction via swizzled LDS transpose (conflict-free).
//   - out_t computed inline: per-block partial (8 rows) + atomicAdd into
//     zero-initialized d_out. Bias added by block 0 only.
//   - h double-buffered in d_ws (2 x 128KB); h0 zeroed via hipMemsetAsync.

#define RDIM 2048
#define BATCH 16
#define TSTEPS 2048
#define NIN 3
#define NOUT 3

__global__ __launch_bounds__(256) void esn_step(
    const float* __restrict__ W,     // [R, R]
    const float* __restrict__ Win,   // [R, NIN]
    const float* __restrict__ x,     // [B, T, NIN]
    const float* __restrict__ Wout,  // [NOUT, R]
    const float* __restrict__ bout,  // [NOUT]
    const float* __restrict__ hprev, // [B, R]
    float* __restrict__ hnext,       // [B, R]
    float* __restrict__ out,         // [B, T, NOUT]
    int t)
{
    __shared__ float red[4][64][32];       // 32 KB: per-wave lane partials
    __shared__ float hblk[8][BATCH];       // block's 8 rows of h_new

    const int tid  = threadIdx.x;
    const int lane = tid & 63;
    const int wave = tid >> 6;
    const int row0 = blockIdx.x * 8 + wave * 2;   // wave handles rows row0, row0+1

    float acc[2][BATCH];
#pragma unroll
    for (int r = 0; r < 2; ++r)
#pragma unroll
        for (int b = 0; b < BATCH; ++b) acc[r][b] = 0.f;

    const float4* W4a = (const float4*)(W + (size_t)row0 * RDIM);
    const float4* W4b = (const float4*)(W + (size_t)(row0 + 1) * RDIM);
    const float4* H4  = (const float4*)hprev;

    // K loop: 2048 floats = 512 float4; 64 lanes -> 8 chunks
#pragma unroll
    for (int c = 0; c < 8; ++c) {
        const int k4 = c * 64 + lane;           // float4 index within a row
        float4 w0 = W4a[k4];
        float4 w1 = W4b[k4];
#pragma unroll
        for (int b = 0; b < BATCH; ++b) {
            float4 h = H4[b * (RDIM / 4) + k4];
            acc[0][b] += w0.x * h.x + w0.y * h.y + w0.z * h.z + w0.w * h.w;
            acc[1][b] += w1.x * h.x + w1.y * h.y + w1.z * h.z + w1.w * h.w;
        }
    }

    // Cross-lane reduction: lane l stores value i at column (i+l)&31 so the
    // 32-lane write is spread over all banks (2-way alias = free), and the
    // reader's per-iteration access pattern is also conflict-free.
#pragma unroll
    for (int i = 0; i < 32; ++i) {
        int r = i >> 4, b = i & 15;
        red[wave][lane][(i + lane) & 31] = acc[r][b];
    }
    __syncthreads();

    if (lane < 32) {
        float s = 0.f;
        for (int l = 0; l < 64; ++l)
            s += red[wave][l][(lane + l) & 31];

        const int r   = lane >> 4;
        const int b   = lane & 15;
        const int row = row0 + r;

        float pre = s;
#pragma unroll
        for (int c = 0; c < NIN; ++c)
            pre += Win[row * NIN + c] * x[((size_t)b * TSTEPS + t) * NIN + c];

        float h = tanhf(pre);
        hnext[(size_t)b * RDIM + row] = h;
        hblk[wave * 2 + r][b] = h;
    }
    __syncthreads();

    // Output projection partial for this block's 8 rows (48 values).
    if (tid < BATCH * NOUT) {
        const int b = tid / NOUT;
        const int k = tid % NOUT;
        float s = 0.f;
#pragma unroll
        for (int rr = 0; rr < 8; ++rr)
            s += Wout[k * RDIM + blockIdx.x * 8 + rr] * hblk[rr][b];
        if (blockIdx.x == 0) s += bout[k];
        atomicAdd(&out[((size_t)b * TSTEPS + t) * NOUT + k], s);
    }
}

extern "C" void kernel_launch(void* const* d_in, const int* in_sizes, int n_in,
                              void* d_out, int out_size, void* d_ws, size_t ws_size,
                              hipStream_t stream) {
    const float* x    = (const float*)d_in[0];  // [16, 2048, 3]
    const float* Win  = (const float*)d_in[1];  // [2048, 3]
    const float* W    = (const float*)d_in[2];  // [2048, 2048]
    const float* Wout = (const float*)d_in[3];  // [3, 2048]
    const float* bout = (const float*)d_in[4];  // [3]
    float* out = (float*)d_out;                 // [16, 2048, 3]

    float* h0 = (float*)d_ws;                   // [B*R]
    float* h1 = h0 + (size_t)BATCH * RDIM;      // [B*R]

    // h_0 = 0; out accumulated via atomics -> zero-init.
    hipMemsetAsync(h0, 0, (size_t)BATCH * RDIM * sizeof(float), stream);
    hipMemsetAsync(d_out, 0, (size_t)out_size * sizeof(float), stream);

    for (int t = 0; t < TSTEPS; ++t) {
        const float* hp = (t & 1) ? h1 : h0;
        float*       hn = (t & 1) ? h0 : h1;
        esn_step<<<dim3(256), dim3(256), 0, stream>>>(
            W, Win, x, Wout, bout, hp, hn, out, t);
    }
}